// Round 9
// baseline (399.907 us; speedup 1.0000x reference)
//
#include <hip/hip_runtime.h>

typedef __bf16 bf16_t;
typedef bf16_t bf16x8 __attribute__((ext_vector_type(8)));
typedef float f32x4 __attribute__((ext_vector_type(4)));

#define MFMA16(a, b, c) __builtin_amdgcn_mfma_f32_16x16x32_bf16(a, b, c, 0, 0, 0)

__device__ __forceinline__ unsigned short f2bf(float f) {
    union { float f; unsigned u; } v; v.f = f;
    unsigned r = v.u + 0x7FFFu + ((v.u >> 16) & 1u);  // RNE
    return (unsigned short)(r >> 16);
}
__device__ __forceinline__ float bf2f(unsigned short h) {
    union { unsigned u; float f; } v; v.u = ((unsigned)h) << 16;
    return v.f;
}
__device__ __forceinline__ unsigned short to_bf(float f) {
    bf16_t b = (bf16_t)f;                 // gfx950 native v_cvt (RNE)
    return __builtin_bit_cast(unsigned short, b);
}

// async global->LDS, 16B per lane; LDS dst is wave-uniform base + lane*16,
// global src address is per-lane.
__device__ __forceinline__ void gll16(const unsigned short* g, unsigned short* l) {
    __builtin_amdgcn_global_load_lds(
        (const __attribute__((address_space(1))) unsigned int*)g,
        (__attribute__((address_space(3))) unsigned int*)l, 16, 0, 0);
}

// ---------------- cast kernels ----------------
__global__ __launch_bounds__(256) void cast_x_kernel(const float* __restrict__ src,
                                                     unsigned short* __restrict__ dst, int n) {
    int i = (blockIdx.x * 256 + threadIdx.x) * 4;
    if (i >= n) return;
    float4 v = *(const float4*)&src[i];
    union { unsigned short e[4]; uint2 u; } p;
    p.e[0] = f2bf(v.x); p.e[1] = f2bf(v.y); p.e[2] = f2bf(v.z); p.e[3] = f2bf(v.w);
    *(uint2*)&dst[i] = p.u;
}

// All four weight transposes in ONE launch.
// src is K x N row-major fp32 (K=2048); dst is N x K row-major bf16 (B^T).
__global__ __launch_bounds__(256) void castT_all_kernel(
    const float* __restrict__ Wq, const float* __restrict__ Wk,
    const float* __restrict__ Wv, const float* __restrict__ Wo,
    unsigned short* __restrict__ Wqkvt, unsigned short* __restrict__ Wot)
{
    __shared__ __align__(16) unsigned short sT[64 * 68];
    int idx = blockIdx.x;            // 2560 = 1024 Wq | 256 Wk | 256 Wv | 1024 Wo
    const float* src; unsigned short* dst; int N; int loc;
    if (idx < 1024)      { src = Wq; dst = Wqkvt;                    N = 2048; loc = idx; }
    else if (idx < 1280) { src = Wk; dst = Wqkvt + 2048ull * 2048;   N = 512;  loc = idx - 1024; }
    else if (idx < 1536) { src = Wv; dst = Wqkvt + 2560ull * 2048;   N = 512;  loc = idx - 1280; }
    else                 { src = Wo; dst = Wot;                      N = 2048; loc = idx - 1536; }
    int nt = loc >> 5;               // K/64 == 32 (K fixed at 2048)
    int kt = loc & 31;
    int k0 = kt * 64, n0 = nt * 64;
    int t = threadIdx.x;
#pragma unroll
    for (int c = t; c < 1024; c += 256) {
        int r = c >> 4, c4 = c & 15;
        float4 v = *(const float4*)&src[(size_t)(k0 + r) * N + n0 + c4 * 4];
        union { unsigned short e[4]; uint2 u; } p;
        p.e[0] = f2bf(v.x); p.e[1] = f2bf(v.y); p.e[2] = f2bf(v.z); p.e[3] = f2bf(v.w);
        *(uint2*)&sT[r * 68 + c4 * 4] = p.u;   // sT[k-row][n-col]
    }
    __syncthreads();
#pragma unroll
    for (int c = t; c < 512; c += 256) {
        int n = c >> 3, cb = c & 7;
        union { unsigned short e[8]; uint4 v; } u;
#pragma unroll
        for (int j = 0; j < 8; ++j) u.e[j] = sT[(cb * 8 + j) * 68 + n];
        *(uint4*)&dst[(size_t)(n0 + n) * 2048 + k0 + cb * 8] = u.v;
    }
}

// ---------------- GEMM: 256x256 tile, 8-phase counted-vmcnt schedule ----------
// (verified passing, R7). See schedule comment table there.
__global__ __launch_bounds__(512) void gemm256_bt(
    const unsigned short* __restrict__ A,
    const unsigned short* __restrict__ Bt,
    float* __restrict__ Cf, unsigned short* __restrict__ Cb,
    int M, int N, int K)
{
    extern __shared__ unsigned short lds[];   // [2][A 16384 | B 16384] ushorts = 131072 B
    const int KT = K >> 6;
    const int NIT = KT >> 1;

    int tid = threadIdx.x;
    int lane = tid & 63, w = tid >> 6;
    int wmi = w >> 2, wni = w & 3;
    int lo = lane & 15, quad = lane >> 4;
    int m0 = blockIdx.y * 256, n0 = blockIdx.x * 256;

    int rsub = lane >> 3;
    int csw  = ((lane & 7) ^ rsub) << 3;

    f32x4 acc[8][4];
#pragma unroll
    for (int i = 0; i < 8; ++i)
#pragma unroll
        for (int j = 0; j < 4; ++j) acc[i][j] = (f32x4){0.f, 0.f, 0.f, 0.f};

    auto stA = [&](int buf, int mp, int T) {
#pragma unroll
        for (int j = 0; j < 2; ++j) {
            int rr = (w * 2 + j) * 8 + rsub;
            gll16(A + (size_t)(m0 + mp * 128 + rr) * K + T * 64 + csw,
                  lds + buf * 32768 + mp * 8192 + (w * 2 + j) * 512);
        }
    };
    auto stB = [&](int buf, int np, int T) {
#pragma unroll
        for (int j = 0; j < 2; ++j) {
            int rr = (w * 2 + j) * 8 + rsub;
            gll16(Bt + (size_t)(n0 + np * 128 + rr) * K + T * 64 + csw,
                  lds + buf * 32768 + 16384 + np * 8192 + (w * 2 + j) * 512);
        }
    };

    auto phase = [&](int buf, int mp, int np, auto stage, bool drain) {
        bf16x8 a[4][2], b2[2][2];
#pragma unroll
        for (int mf = 0; mf < 4; ++mf)
#pragma unroll
            for (int k2 = 0; k2 < 2; ++k2) {
                int r = mp * 128 + wmi * 64 + mf * 16 + lo;
                int u = quad + k2 * 4;
                a[mf][k2] = *(const bf16x8*)&lds[buf * 32768 + r * 64 + ((u ^ (lo & 7)) << 3)];
            }
#pragma unroll
        for (int nf = 0; nf < 2; ++nf)
#pragma unroll
            for (int k2 = 0; k2 < 2; ++k2) {
                int r = np * 128 + wni * 32 + nf * 16 + lo;
                int u = quad + k2 * 4;
                b2[nf][k2] = *(const bf16x8*)&lds[buf * 32768 + 16384 + r * 64 + ((u ^ (lo & 7)) << 3)];
            }
        stage();
        __builtin_amdgcn_s_barrier();
        __builtin_amdgcn_sched_barrier(0);
        __builtin_amdgcn_s_setprio(1);
#pragma unroll
        for (int mf = 0; mf < 4; ++mf)
#pragma unroll
            for (int nf = 0; nf < 2; ++nf) {
                f32x4 z = acc[mp * 4 + mf][np * 2 + nf];
                z = MFMA16(a[mf][0], b2[nf][0], z);
                z = MFMA16(a[mf][1], b2[nf][1], z);
                acc[mp * 4 + mf][np * 2 + nf] = z;
            }
        __builtin_amdgcn_s_setprio(0);
        if (drain) asm volatile("s_waitcnt vmcnt(0)" ::: "memory");
        else       asm volatile("s_waitcnt vmcnt(6)" ::: "memory");
        __builtin_amdgcn_s_barrier();
        __builtin_amdgcn_sched_barrier(0);
    };
    auto nop = [&] {};

    stA(0, 0, 0); stB(0, 0, 0); stA(0, 1, 0); stB(0, 1, 0);
    stA(1, 0, 1); stB(1, 0, 1);
    asm volatile("s_waitcnt vmcnt(4)" ::: "memory");
    __builtin_amdgcn_s_barrier();
    __builtin_amdgcn_sched_barrier(0);

    for (int i = 0; i < NIT - 1; ++i) {
        int T1 = 2 * i + 1, T2 = 2 * i + 2, T3 = 2 * i + 3;
        phase(0, 0, 0, [&] { stA(1, 1, T1); }, false);
        phase(0, 0, 1, [&] { stB(1, 1, T1); }, false);
        phase(0, 1, 0, [&] { stA(0, 0, T2); }, false);
        phase(0, 1, 1, [&] { stB(0, 0, T2); }, false);
        phase(1, 0, 0, [&] { stA(0, 1, T2); }, false);
        phase(1, 0, 1, [&] { stB(0, 1, T2); }, false);
        phase(1, 1, 0, [&] { stA(1, 0, T3); }, false);
        phase(1, 1, 1, [&] { stB(1, 0, T3); }, false);
    }
    {
        int T1 = KT - 1;
        phase(0, 0, 0, [&] { stA(1, 1, T1); }, false);
        phase(0, 0, 1, [&] { stB(1, 1, T1); }, true);
        phase(0, 1, 0, nop, false);
        phase(0, 1, 1, nop, false);
        phase(1, 0, 0, nop, false);
        phase(1, 0, 1, nop, false);
        phase(1, 1, 0, nop, false);
        phase(1, 1, 1, nop, false);
    }

#pragma unroll
    for (int mi = 0; mi < 8; ++mi) {
        int mp = mi >> 2, mf = mi & 3;
        int row_base = m0 + mp * 128 + wmi * 64 + mf * 16 + quad * 4;
#pragma unroll
        for (int ni = 0; ni < 4; ++ni) {
            int np = ni >> 1, nf = ni & 1;
            int col = n0 + np * 128 + wni * 32 + nf * 16 + lo;
#pragma unroll
            for (int r = 0; r < 4; ++r) {
                int row = row_base + r;
                if (Cf) Cf[(size_t)row * N + col] = acc[mi][ni][r];
                else    Cb[(size_t)row * N + col] = f2bf(acc[mi][ni][r]);
            }
        }
    }
}

// ---------------- GEMM: 256x128 tile, 4-phase counted-vmcnt schedule ----------
// (verified passing, R8). See schedule comment table there.
__global__ __launch_bounds__(512) void gemm256x128_bt(
    const unsigned short* __restrict__ A,
    const unsigned short* __restrict__ Bt,
    float* __restrict__ Cf, unsigned short* __restrict__ Cb,
    int M, int N, int K)
{
    extern __shared__ unsigned short lds[];   // A: 2x16384 @0 | B: 3x8192 @32768 = 114688 B
    const int KT = K >> 6;
    const int NIT = KT >> 1;

    int tid = threadIdx.x;
    int lane = tid & 63, w = tid >> 6;
    int wmi = w >> 2, wni = w & 3;
    int lo = lane & 15, quad = lane >> 4;
    int m0 = blockIdx.y * 256, n0 = blockIdx.x * 128;

    int rsub = lane >> 3;
    int csw  = ((lane & 7) ^ rsub) << 3;

    f32x4 acc[8][2];
#pragma unroll
    for (int i = 0; i < 8; ++i)
#pragma unroll
        for (int j = 0; j < 2; ++j) acc[i][j] = (f32x4){0.f, 0.f, 0.f, 0.f};

    auto stA = [&](int d, int u, int T) {
        int Tc = T >= KT ? T - KT : T;
#pragma unroll
        for (int j = 0; j < 2; ++j) {
            int rr = u * 128 + (w * 2 + j) * 8 + rsub;
            gll16(A + (size_t)(m0 + rr) * K + Tc * 64 + csw,
                  lds + d * 16384 + u * 8192 + (w * 2 + j) * 512);
        }
    };
    auto stB = [&](int T) {
        int t3 = T % 3;
        int Tc = T >= KT ? T - KT : T;
#pragma unroll
        for (int j = 0; j < 2; ++j) {
            int rr = (w * 2 + j) * 8 + rsub;
            gll16(Bt + (size_t)(n0 + rr) * K + Tc * 64 + csw,
                  lds + 32768 + t3 * 8192 + (w * 2 + j) * 512);
        }
    };

    auto phase = [&](int d, int t3, int mp, auto stage, bool w8) {
        bf16x8 a[4][2], b2[2][2];
#pragma unroll
        for (int mf = 0; mf < 4; ++mf)
#pragma unroll
            for (int k2 = 0; k2 < 2; ++k2) {
                int r = mp * 128 + wmi * 64 + mf * 16 + lo;
                int u = quad + k2 * 4;
                a[mf][k2] = *(const bf16x8*)&lds[d * 16384 + r * 64 + ((u ^ (lo & 7)) << 3)];
            }
#pragma unroll
        for (int nf = 0; nf < 2; ++nf)
#pragma unroll
            for (int k2 = 0; k2 < 2; ++k2) {
                int r = wni * 32 + nf * 16 + lo;
                int u = quad + k2 * 4;
                b2[nf][k2] = *(const bf16x8*)&lds[32768 + t3 * 8192 + r * 64 + ((u ^ (lo & 7)) << 3)];
            }
        stage();
        __builtin_amdgcn_s_barrier();
        __builtin_amdgcn_sched_barrier(0);
        __builtin_amdgcn_s_setprio(1);
#pragma unroll
        for (int mf = 0; mf < 4; ++mf)
#pragma unroll
            for (int nf = 0; nf < 2; ++nf) {
                f32x4 z = acc[mp * 4 + mf][nf];
                z = MFMA16(a[mf][0], b2[nf][0], z);
                z = MFMA16(a[mf][1], b2[nf][1], z);
                acc[mp * 4 + mf][nf] = z;
            }
        __builtin_amdgcn_s_setprio(0);
        if (w8) asm volatile("s_waitcnt vmcnt(8)" ::: "memory");
        else    asm volatile("s_waitcnt vmcnt(6)" ::: "memory");
        __builtin_amdgcn_s_barrier();
        __builtin_amdgcn_sched_barrier(0);
    };

    stA(0, 0, 0); stA(0, 1, 0); stB(0);
    stA(1, 0, 1); stB(1);
    asm volatile("s_waitcnt vmcnt(4)" ::: "memory");
    __builtin_amdgcn_s_barrier();
    __builtin_amdgcn_sched_barrier(0);

    for (int i = 0; i < NIT; ++i) {
        int T0 = 2 * i, T1 = 2 * i + 1, T2 = 2 * i + 2, T3 = 2 * i + 3;
        int b0 = T0 % 3, b1 = T1 % 3;
        phase(0, b0, 0, [&] { stA(1, 1, T1); stB(T2); }, true);
        phase(0, b0, 1, [&] { stA(0, 0, T2); },          false);
        phase(1, b1, 0, [&] { stA(0, 1, T2); stB(T3); }, true);
        phase(1, b1, 1, [&] { stA(1, 0, T3); },          false);
    }

#pragma unroll
    for (int mi = 0; mi < 8; ++mi) {
        int mp = mi >> 2, mf = mi & 3;
        int row_base = m0 + mp * 128 + wmi * 64 + mf * 16 + quad * 4;
#pragma unroll
        for (int nf = 0; nf < 2; ++nf) {
            int col = n0 + wni * 32 + nf * 16 + lo;
#pragma unroll
            for (int r = 0; r < 4; ++r) {
                int row = row_base + r;
                if (Cf) Cf[(size_t)row * N + col] = acc[mi][nf][r];
                else    Cb[(size_t)row * N + col] = f2bf(acc[mi][nf][r]);
            }
        }
    }
}

// ---------------- RMSNorm + RoPE (+ scatter to outputs) ----------------
// qkv: (B*S, 3072) bf16 rows = [q 2048 | k 512 | v 512]
__global__ __launch_bounds__(256) void rmsrope_kernel(
    const unsigned short* __restrict__ qkv,
    const float* __restrict__ cosb, const float* __restrict__ sinb,
    const float* __restrict__ q_scale, const float* __restrict__ k_scale,
    unsigned short* __restrict__ q_attn, unsigned short* __restrict__ k_attn,
    float* __restrict__ k_out, float* __restrict__ v_out)
{
    int wid = blockIdx.x * 4 + (threadIdx.x >> 6);   // one wave per 64-elem row
    int lane = threadIdx.x & 63;
    int t = wid % 48;          // 0..31 q-head, 32..39 k-group, 40..47 v-group
    int bs = wid / 48;         // 0..4095
    int b = bs >> 11, s = bs & 2047;

    if (t >= 40) {             // v: straight copy to output (b,g,s,d) fp32
        int g = t - 40;
        float val = bf2f(qkv[(size_t)bs * 3072 + 2560 + g * 64 + lane]);
        v_out[(size_t)((b * 8 + g) * 2048 + s) * 64 + lane] = val;
        return;
    }
    bool is_q = (t < 32);
    int col = is_q ? (t * 64) : (2048 + (t - 32) * 64);
    float val = bf2f(qkv[(size_t)bs * 3072 + col + lane]);
    float ss = val * val;
#pragma unroll
    for (int m = 1; m < 64; m <<= 1) ss += __shfl_xor(ss, m);
    float rs = rsqrtf(ss * (1.0f / 64.0f) + 1e-6f);
    float scl = is_q ? q_scale[lane] : k_scale[lane];
    float xn = val * rs * scl;
    float other = __shfl_xor(xn, 32);
    float rot = (lane < 32) ? -other : other;     // [-x2, x1]
    float o = xn * cosb[s * 64 + lane] + rot * sinb[s * 64 + lane];
    if (is_q) {
        // fold 1/sqrt(D)=0.125 and log2(e) into q (attention works in exp2 domain)
        q_attn[(size_t)((b * 32 + t) * 2048 + s) * 64 + lane] = to_bf(o * (0.125f * 1.44269504f));
    } else {
        int g = t - 32;
        size_t idx = (size_t)((b * 8 + g) * 2048 + s) * 64 + lane;
        k_attn[idx] = to_bf(o);
        k_out[idx] = o;
    }
}

// ---------------- V transpose: qkv v-cols -> vt (b,g,d,s) bf16 ----------------
__global__ __launch_bounds__(256) void vtrans_kernel(
    const unsigned short* __restrict__ qkv, unsigned short* __restrict__ vt)
{
    __shared__ __align__(16) unsigned short sT[64 * 68];
    int idx = blockIdx.x;            // B*G*32 = 512
    int st = idx & 31, g = (idx >> 5) & 7, b = idx >> 8;
    int tid = threadIdx.x;
#pragma unroll
    for (int c = tid; c < 512; c += 256) {
        int r = c >> 3, cb = c & 7;
        *(uint4*)&sT[r * 68 + cb * 8] =
            *(const uint4*)&qkv[(size_t)(b * 2048 + st * 64 + r) * 3072 + 2560 + g * 64 + cb * 8];
    }
    __syncthreads();
#pragma unroll
    for (int c = tid; c < 512; c += 256) {
        int d = c >> 3, cb = c & 7;
        union { unsigned short e[8]; uint4 v; } u;
#pragma unroll
        for (int j = 0; j < 8; ++j) u.e[j] = sT[(cb * 8 + j) * 68 + d];
        *(uint4*)&vt[((size_t)(b * 8 + g) * 64 + d) * 2048 + st * 64 + cb * 8] = u.v;
    }
}

// ---------------- flash attention, causal, GQA ----------------
// R8 post-mortem: attn at 90us, MfmaUtil 18% — the 2-phase stage->barrier loop
// is barrier/stage-overhead dominated (m233: stage+vmcnt+bar ~72% of a 2-phase
// loop). THIS version doubles q-rows per wave (32 -> 64): each wave runs 72
// MFMA per staged 16KB K/V tile instead of 36 — block-iterations (barriers +
// stages) HALVE, K/V bytes per MFMA halve. Rows [64qb, 64qb+64) need kv tiles
// 0..qb, only kt==qb masked. Grid 512 blocks (4 waves = 4 heads each), first
// 256 = qb 31..16 (long tasks), second 256 = qb 15..0 (shorts backfill).
// acc 64 + l 16 + qf 32 + transients: ~160 regs, 2 waves/SIMD sufficient
// (grid offers only 2 blocks/CU).
__global__ __launch_bounds__(256, 2) void attn_kernel(
    const unsigned short* __restrict__ q_attn,   // (b,h,s,d) bf16, pre-scaled (log2 domain)
    const unsigned short* __restrict__ k_attn,   // (b,g,s,d) bf16 post-rope
    const unsigned short* __restrict__ vt,       // (b,g,d,s) bf16
    unsigned short* __restrict__ ctx)            // (b,s,h*d) bf16
{
    __shared__ __align__(16) unsigned short sK[2][4096];   // 16 KB (2 x 64x64 bf16)
    __shared__ __align__(16) unsigned short sV[2][4096];   // 16 KB
    __shared__ __align__(16) unsigned short sP[4][16 * 68];// 8.5 KB (wave-private)

    int w = threadIdx.x >> 6;        // wave in block = head-in-group, 0..3
    int lane = threadIdx.x & 63;

    int g = blockIdx.x & 7;          // XCD swizzle: (b,g) working set pinned per XCD
    int rest = blockIdx.x >> 3;      // 0..63
    int b = rest & 1;
    int qb = 31 - (rest >> 1);       // 31..16 in first 256 blocks, then 15..0
    int h = g * 4 + w;

    int lo = lane & 15, quad = lane >> 4;
    unsigned short* sPw = sP[w];

    const unsigned short* Qb = q_attn + (size_t)(b * 32 + h) * 2048 * 64;
    const unsigned short* Kb = k_attn + (size_t)(b * 8 + g) * 2048 * 64;
    const unsigned short* Vb = vt + (size_t)(b * 8 + g) * 64 * 2048;

    int nt = qb + 1;                 // kv tiles 0..qb (tile = 64 kv)

    int rsub = lane >> 3;                  // 0..7 (== row & 7 within chunk)
    int csw  = ((lane & 7) ^ rsub) << 3;   // ushort units

    auto STAGE = [&](int buf, int kt) {
#pragma unroll
        for (int i = 0; i < 2; ++i) {
            int c = w + i * 4;             // this wave's chunks: w, w+4
            gll16(Kb + (size_t)(kt * 64 + c * 8 + rsub) * 64 + csw, &sK[buf][c * 512]);
            gll16(Vb + (size_t)(c * 8 + rsub) * 2048 + kt * 64 + csw, &sV[buf][c * 512]);
        }
    };

    const bf16_t one = (bf16_t)1.0f;
    const bf16x8 vone = {one, one, one, one, one, one, one, one};

    // Q fragments: 64 rows = 4 sub-tiles of 16 (32 VGPR)
    bf16x8 qf[4][2];
#pragma unroll
    for (int mt = 0; mt < 4; ++mt)
#pragma unroll
        for (int h2 = 0; h2 < 2; ++h2)
            qf[mt][h2] = *(const bf16x8*)&Qb[(size_t)(qb * 64 + mt * 16 + lo) * 64 + h2 * 32 + quad * 8];

    f32x4 o_acc[4][4];
    f32x4 l_acc[4];
#pragma unroll
    for (int mt = 0; mt < 4; ++mt) {
        l_acc[mt] = (f32x4){0.f, 0.f, 0.f, 0.f};
#pragma unroll
        for (int j = 0; j < 4; ++j) o_acc[mt][j] = (f32x4){0.f, 0.f, 0.f, 0.f};
    }

    STAGE(0, 0);
    __syncthreads();                 // drains vmcnt(0): buffer 0 complete

    int cur = 0;
    for (int kt = 0; kt < nt; ++kt) {
        if (kt + 1 < nt) STAGE(cur ^ 1, kt + 1);   // issue-early, in flight during compute

        const char* sKc = (const char*)sK[cur];
        const char* sVc = (const char*)sV[cur];
        bool domask = (kt == nt - 1);

#pragma unroll
        for (int mt = 0; mt < 4; ++mt) {
            f32x4 sc[4];
            __builtin_amdgcn_s_setprio(1);
#pragma unroll
            for (int ct = 0; ct < 4; ++ct) {
                int krow = ct * 16 + lo;
                int rsw = (krow & 7) << 4;
                bf16x8 kf0 = *(const bf16x8*)(sKc + (krow << 7) + (((quad << 4)) ^ rsw));
                bf16x8 kf1 = *(const bf16x8*)(sKc + (krow << 7) + (((1 << 6) | (quad << 4)) ^ rsw));
                f32x4 z = (f32x4){0.f, 0.f, 0.f, 0.f};
                z = MFMA16(qf[mt][0], kf0, z);
                z = MFMA16(qf[mt][1], kf1, z);
                sc[ct] = z;
            }
            __builtin_amdgcn_s_setprio(0);
            if (domask) {        // diagonal region: causal mask (absolute indices)
                int qrow0 = qb * 64 + mt * 16 + quad * 4;
#pragma unroll
                for (int ct = 0; ct < 4; ++ct)
#pragma unroll
                    for (int r = 0; r < 4; ++r)
                        if (kt * 64 + ct * 16 + lo > qrow0 + r) sc[ct][r] = -INFINITY;
            }
            // bare exp2 (scores bounded); masked -> 2^-inf = 0
#pragma unroll
            for (int ct = 0; ct < 4; ++ct)
#pragma unroll
                for (int r = 0; r < 4; ++r)
                    sc[ct][r] = __builtin_amdgcn_exp2f(sc[ct][r]);

            // P: C-layout -> LDS (wave-private, stride 68: conflict-free)
#pragma unroll
            for (int ct = 0; ct < 4; ++ct)
#pragma unroll
                for (int r = 0; r < 4; ++r)
                    sPw[(quad * 4 + r) * 68 + ct * 16 + lo] = to_bf(sc[ct][r]);

            bf16x8 pf0 = *(const bf16x8*)&sPw[lo * 68 + quad * 8];
            bf16x8 pf1 = *(const bf16x8*)&sPw[lo * 68 + 32 + quad * 8];

            __builtin_amdgcn_s_setprio(1);
            // row-sum l via ones-MFMA (every output column = rowsum, C-layout)
            l_acc[mt] = MFMA16(pf0, vone, l_acc[mt]);
            l_acc[mt] = MFMA16(pf1, vone, l_acc[mt]);

            // PV: V fragments read JIT from LDS
#pragma unroll
            for (int nt2 = 0; nt2 < 4; ++nt2) {
                int vrow = nt2 * 16 + lo;
                int rsw = (vrow & 7) << 4;
                bf16x8 vf0 = *(const bf16x8*)(sVc + (vrow << 7) + (((quad << 4)) ^ rsw));
                bf16x8 vf1 = *(const bf16x8*)(sVc + (vrow << 7) + (((1 << 6) | (quad << 4)) ^ rsw));
                f32x4 oo = o_acc[mt][nt2];
                oo = MFMA16(pf0, vf0, oo);
                oo = MFMA16(pf1, vf1, oo);
                o_acc[mt][nt2] = oo;
            }
            __builtin_amdgcn_s_setprio(0);
        }

        __syncthreads();             // staged buffer landed; all waves done with cur
        cur ^= 1;
    }

    // ---- epilogue ----
#pragma unroll
    for (int mt = 0; mt < 4; ++mt)
#pragma unroll
        for (int r = 0; r < 4; ++r) {
            float inv = 1.0f / l_acc[mt][r];
            int row = qb * 64 + mt * 16 + quad * 4 + r;
#pragma unroll
            for (int nt2 = 0; nt2 < 4; ++nt2) {
                size_t oi = ((size_t)(b * 2048 + row)) * 2048 + h * 64 + nt2 * 16 + lo;
                ctx[oi] = to_bf(o_acc[mt][nt2][r] * inv);
            }
        }
}

// ---------------- launch ----------------
extern "C" void kernel_launch(void* const* d_in, const int* in_sizes, int n_in,
                              void* d_out, int out_size, void* d_ws, size_t ws_size,
                              hipStream_t stream)
{
    (void)in_sizes; (void)n_in; (void)out_size; (void)ws_size;
    const float* x       = (const float*)d_in[0];
    // d_in[1] = mask: ignored (causal mask recomputed analytically)
    const float* cosb    = (const float*)d_in[2];
    const float* sinb    = (const float*)d_in[3];
    const float* Wq      = (const float*)d_in[4];
    const float* Wk      = (const float*)d_in[5];
    const float* Wv      = (const float*)d_in[6];
    const float* Wo      = (const float*)d_in[7];
    const float* q_scale = (const float*)d_in[8];
    const float* k_scale = (const float*)d_in[9];

    float* out   = (float*)d_out;                 // (2,2048,2048)
    float* k_out = out + 8388608;                 // (2,8,2048,64)
    float* v_out = k_out + 2097152;               // (2,8,2048,64)

    // one-time: allow big dynamic LDS for the pipelined GEMMs
    static bool attr_done = false;
    if (!attr_done) {
        hipFuncSetAttribute((const void*)gemm256_bt,
                            hipFuncAttributeMaxDynamicSharedMemorySize, 131072);
        hipFuncSetAttribute((const void*)gemm256x128_bt,
                            hipFuncAttributeMaxDynamicSharedMemorySize, 114688);
        attr_done = true;
    }

    char* ws = (char*)d_ws;
    size_t off = 0;
    auto alloc = [&](size_t bytes) {
        char* p = ws + off; off += (bytes + 255) & ~(size_t)255; return p;
    };
    unsigned short* x_bf   = (unsigned short*)alloc(4096ull * 2048 * 2);   // 16 MB
    unsigned short* Wqkvt  = (unsigned short*)alloc(3072ull * 2048 * 2);   // 12 MB
    unsigned short* Wot    = (unsigned short*)alloc(2048ull * 2048 * 2);   //  8 MB
    unsigned short* qkv    = (unsigned short*)alloc(4096ull * 3072 * 2);   // 24 MB
    unsigned short* q_attn = (unsigned short*)alloc(4096ull * 2048 * 2);   // 16 MB
    unsigned short* k_attn = (unsigned short*)alloc(2048ull * 2048 * 2);   //  4 MB
    unsigned short* vt     = (unsigned short*)alloc(2097152ull * 2);       //  4 MB
    unsigned short* ctx    = (unsigned short*)alloc(4096ull * 2048 * 2);   // 16 MB

    cast_x_kernel<<<8192, 256, 0, stream>>>(x, x_bf, 8388608);
    castT_all_kernel<<<2560, 256, 0, stream>>>(Wq, Wk, Wv, Wo, Wqkvt, Wot);

    // qkv = x @ [Wq|Wk|Wv]  (bf16 out)
    gemm256_bt<<<dim3(12, 16), 512, 131072, stream>>>(x_bf, Wqkvt, nullptr, qkv, 4096, 3072, 2048);

    rmsrope_kernel<<<49152, 256, 0, stream>>>(qkv, cosb, sinb, q_scale, k_scale,
                                              q_attn, k_attn, k_out, v_out);
    vtrans_kernel<<<512, 256, 0, stream>>>(qkv, vt);

    attn_kernel<<<512, 256, 0, stream>>>(q_attn, k_attn, vt, ctx);

    // out = ctx @ Wo  (fp32 out) — 256x128 tiles: 256 blocks, every CU busy
    gemm256x128_bt<<<dim3(16, 16), 512, 114688, stream>>>(ctx, Wot, out, nullptr, 4096, 2048, 2048);
}

// Round 10
// 336.009 us; speedup vs baseline: 1.1902x; 1.1902x over previous
//
#include <hip/hip_runtime.h>

typedef __bf16 bf16_t;
typedef bf16_t bf16x8 __attribute__((ext_vector_type(8)));
typedef float f32x4 __attribute__((ext_vector_type(4)));

#define MFMA16(a, b, c) __builtin_amdgcn_mfma_f32_16x16x32_bf16(a, b, c, 0, 0, 0)

__device__ __forceinline__ unsigned short f2bf(float f) {
    union { float f; unsigned u; } v; v.f = f;
    unsigned r = v.u + 0x7FFFu + ((v.u >> 16) & 1u);  // RNE
    return (unsigned short)(r >> 16);
}
__device__ __forceinline__ float bf2f(unsigned short h) {
    union { unsigned u; float f; } v; v.u = ((unsigned)h) << 16;
    return v.f;
}
__device__ __forceinline__ unsigned short to_bf(float f) {
    bf16_t b = (bf16_t)f;                 // gfx950 native v_cvt (RNE)
    return __builtin_bit_cast(unsigned short, b);
}

// async global->LDS, 16B per lane; LDS dst is wave-uniform base + lane*16,
// global src address is per-lane.
__device__ __forceinline__ void gll16(const unsigned short* g, unsigned short* l) {
    __builtin_amdgcn_global_load_lds(
        (const __attribute__((address_space(1))) unsigned int*)g,
        (__attribute__((address_space(3))) unsigned int*)l, 16, 0, 0);
}

// ---------------- cast kernels ----------------
__global__ __launch_bounds__(256) void cast_x_kernel(const float* __restrict__ src,
                                                     unsigned short* __restrict__ dst, int n) {
    int i = (blockIdx.x * 256 + threadIdx.x) * 4;
    if (i >= n) return;
    float4 v = *(const float4*)&src[i];
    union { unsigned short e[4]; uint2 u; } p;
    p.e[0] = f2bf(v.x); p.e[1] = f2bf(v.y); p.e[2] = f2bf(v.z); p.e[3] = f2bf(v.w);
    *(uint2*)&dst[i] = p.u;
}

// All four weight transposes in ONE launch.
// src is K x N row-major fp32 (K=2048); dst is N x K row-major bf16 (B^T).
__global__ __launch_bounds__(256) void castT_all_kernel(
    const float* __restrict__ Wq, const float* __restrict__ Wk,
    const float* __restrict__ Wv, const float* __restrict__ Wo,
    unsigned short* __restrict__ Wqkvt, unsigned short* __restrict__ Wot)
{
    __shared__ __align__(16) unsigned short sT[64 * 68];
    int idx = blockIdx.x;            // 2560 = 1024 Wq | 256 Wk | 256 Wv | 1024 Wo
    const float* src; unsigned short* dst; int N; int loc;
    if (idx < 1024)      { src = Wq; dst = Wqkvt;                    N = 2048; loc = idx; }
    else if (idx < 1280) { src = Wk; dst = Wqkvt + 2048ull * 2048;   N = 512;  loc = idx - 1024; }
    else if (idx < 1536) { src = Wv; dst = Wqkvt + 2560ull * 2048;   N = 512;  loc = idx - 1280; }
    else                 { src = Wo; dst = Wot;                      N = 2048; loc = idx - 1536; }
    int nt = loc >> 5;               // K/64 == 32 (K fixed at 2048)
    int kt = loc & 31;
    int k0 = kt * 64, n0 = nt * 64;
    int t = threadIdx.x;
#pragma unroll
    for (int c = t; c < 1024; c += 256) {
        int r = c >> 4, c4 = c & 15;
        float4 v = *(const float4*)&src[(size_t)(k0 + r) * N + n0 + c4 * 4];
        union { unsigned short e[4]; uint2 u; } p;
        p.e[0] = f2bf(v.x); p.e[1] = f2bf(v.y); p.e[2] = f2bf(v.z); p.e[3] = f2bf(v.w);
        *(uint2*)&sT[r * 68 + c4 * 4] = p.u;   // sT[k-row][n-col]
    }
    __syncthreads();
#pragma unroll
    for (int c = t; c < 512; c += 256) {
        int n = c >> 3, cb = c & 7;
        union { unsigned short e[8]; uint4 v; } u;
#pragma unroll
        for (int j = 0; j < 8; ++j) u.e[j] = sT[(cb * 8 + j) * 68 + n];
        *(uint4*)&dst[(size_t)(n0 + n) * 2048 + k0 + cb * 8] = u.v;
    }
}

// ---------------- GEMM: 256x256 tile, 8-phase counted-vmcnt schedule ----------
// (verified passing, R7). See schedule comment table there.
__global__ __launch_bounds__(512) void gemm256_bt(
    const unsigned short* __restrict__ A,
    const unsigned short* __restrict__ Bt,
    float* __restrict__ Cf, unsigned short* __restrict__ Cb,
    int M, int N, int K)
{
    extern __shared__ unsigned short lds[];   // [2][A 16384 | B 16384] ushorts = 131072 B
    const int KT = K >> 6;
    const int NIT = KT >> 1;

    int tid = threadIdx.x;
    int lane = tid & 63, w = tid >> 6;
    int wmi = w >> 2, wni = w & 3;
    int lo = lane & 15, quad = lane >> 4;
    int m0 = blockIdx.y * 256, n0 = blockIdx.x * 256;

    int rsub = lane >> 3;
    int csw  = ((lane & 7) ^ rsub) << 3;

    f32x4 acc[8][4];
#pragma unroll
    for (int i = 0; i < 8; ++i)
#pragma unroll
        for (int j = 0; j < 4; ++j) acc[i][j] = (f32x4){0.f, 0.f, 0.f, 0.f};

    auto stA = [&](int buf, int mp, int T) {
#pragma unroll
        for (int j = 0; j < 2; ++j) {
            int rr = (w * 2 + j) * 8 + rsub;
            gll16(A + (size_t)(m0 + mp * 128 + rr) * K + T * 64 + csw,
                  lds + buf * 32768 + mp * 8192 + (w * 2 + j) * 512);
        }
    };
    auto stB = [&](int buf, int np, int T) {
#pragma unroll
        for (int j = 0; j < 2; ++j) {
            int rr = (w * 2 + j) * 8 + rsub;
            gll16(Bt + (size_t)(n0 + np * 128 + rr) * K + T * 64 + csw,
                  lds + buf * 32768 + 16384 + np * 8192 + (w * 2 + j) * 512);
        }
    };

    auto phase = [&](int buf, int mp, int np, auto stage, bool drain) {
        bf16x8 a[4][2], b2[2][2];
#pragma unroll
        for (int mf = 0; mf < 4; ++mf)
#pragma unroll
            for (int k2 = 0; k2 < 2; ++k2) {
                int r = mp * 128 + wmi * 64 + mf * 16 + lo;
                int u = quad + k2 * 4;
                a[mf][k2] = *(const bf16x8*)&lds[buf * 32768 + r * 64 + ((u ^ (lo & 7)) << 3)];
            }
#pragma unroll
        for (int nf = 0; nf < 2; ++nf)
#pragma unroll
            for (int k2 = 0; k2 < 2; ++k2) {
                int r = np * 128 + wni * 32 + nf * 16 + lo;
                int u = quad + k2 * 4;
                b2[nf][k2] = *(const bf16x8*)&lds[buf * 32768 + 16384 + r * 64 + ((u ^ (lo & 7)) << 3)];
            }
        stage();
        __builtin_amdgcn_s_barrier();
        __builtin_amdgcn_sched_barrier(0);
        __builtin_amdgcn_s_setprio(1);
#pragma unroll
        for (int mf = 0; mf < 4; ++mf)
#pragma unroll
            for (int nf = 0; nf < 2; ++nf) {
                f32x4 z = acc[mp * 4 + mf][np * 2 + nf];
                z = MFMA16(a[mf][0], b2[nf][0], z);
                z = MFMA16(a[mf][1], b2[nf][1], z);
                acc[mp * 4 + mf][np * 2 + nf] = z;
            }
        __builtin_amdgcn_s_setprio(0);
        if (drain) asm volatile("s_waitcnt vmcnt(0)" ::: "memory");
        else       asm volatile("s_waitcnt vmcnt(6)" ::: "memory");
        __builtin_amdgcn_s_barrier();
        __builtin_amdgcn_sched_barrier(0);
    };
    auto nop = [&] {};

    stA(0, 0, 0); stB(0, 0, 0); stA(0, 1, 0); stB(0, 1, 0);
    stA(1, 0, 1); stB(1, 0, 1);
    asm volatile("s_waitcnt vmcnt(4)" ::: "memory");
    __builtin_amdgcn_s_barrier();
    __builtin_amdgcn_sched_barrier(0);

    for (int i = 0; i < NIT - 1; ++i) {
        int T1 = 2 * i + 1, T2 = 2 * i + 2, T3 = 2 * i + 3;
        phase(0, 0, 0, [&] { stA(1, 1, T1); }, false);
        phase(0, 0, 1, [&] { stB(1, 1, T1); }, false);
        phase(0, 1, 0, [&] { stA(0, 0, T2); }, false);
        phase(0, 1, 1, [&] { stB(0, 0, T2); }, false);
        phase(1, 0, 0, [&] { stA(0, 1, T2); }, false);
        phase(1, 0, 1, [&] { stB(0, 1, T2); }, false);
        phase(1, 1, 0, [&] { stA(1, 0, T3); }, false);
        phase(1, 1, 1, [&] { stB(1, 0, T3); }, false);
    }
    {
        int T1 = KT - 1;
        phase(0, 0, 0, [&] { stA(1, 1, T1); }, false);
        phase(0, 0, 1, [&] { stB(1, 1, T1); }, true);
        phase(0, 1, 0, nop, false);
        phase(0, 1, 1, nop, false);
        phase(1, 0, 0, nop, false);
        phase(1, 0, 1, nop, false);
        phase(1, 1, 0, nop, false);
        phase(1, 1, 1, nop, false);
    }

#pragma unroll
    for (int mi = 0; mi < 8; ++mi) {
        int mp = mi >> 2, mf = mi & 3;
        int row_base = m0 + mp * 128 + wmi * 64 + mf * 16 + quad * 4;
#pragma unroll
        for (int ni = 0; ni < 4; ++ni) {
            int np = ni >> 1, nf = ni & 1;
            int col = n0 + np * 128 + wni * 32 + nf * 16 + lo;
#pragma unroll
            for (int r = 0; r < 4; ++r) {
                int row = row_base + r;
                if (Cf) Cf[(size_t)row * N + col] = acc[mi][ni][r];
                else    Cb[(size_t)row * N + col] = f2bf(acc[mi][ni][r]);
            }
        }
    }
}

// ---------------- GEMM: 256x128 tile, 4-phase counted-vmcnt schedule ----------
// (verified passing, R8). See schedule comment table there.
__global__ __launch_bounds__(512) void gemm256x128_bt(
    const unsigned short* __restrict__ A,
    const unsigned short* __restrict__ Bt,
    float* __restrict__ Cf, unsigned short* __restrict__ Cb,
    int M, int N, int K)
{
    extern __shared__ unsigned short lds[];   // A: 2x16384 @0 | B: 3x8192 @32768 = 114688 B
    const int KT = K >> 6;
    const int NIT = KT >> 1;

    int tid = threadIdx.x;
    int lane = tid & 63, w = tid >> 6;
    int wmi = w >> 2, wni = w & 3;
    int lo = lane & 15, quad = lane >> 4;
    int m0 = blockIdx.y * 256, n0 = blockIdx.x * 128;

    int rsub = lane >> 3;
    int csw  = ((lane & 7) ^ rsub) << 3;

    f32x4 acc[8][2];
#pragma unroll
    for (int i = 0; i < 8; ++i)
#pragma unroll
        for (int j = 0; j < 2; ++j) acc[i][j] = (f32x4){0.f, 0.f, 0.f, 0.f};

    auto stA = [&](int d, int u, int T) {
        int Tc = T >= KT ? T - KT : T;
#pragma unroll
        for (int j = 0; j < 2; ++j) {
            int rr = u * 128 + (w * 2 + j) * 8 + rsub;
            gll16(A + (size_t)(m0 + rr) * K + Tc * 64 + csw,
                  lds + d * 16384 + u * 8192 + (w * 2 + j) * 512);
        }
    };
    auto stB = [&](int T) {
        int t3 = T % 3;
        int Tc = T >= KT ? T - KT : T;
#pragma unroll
        for (int j = 0; j < 2; ++j) {
            int rr = (w * 2 + j) * 8 + rsub;
            gll16(Bt + (size_t)(n0 + rr) * K + Tc * 64 + csw,
                  lds + 32768 + t3 * 8192 + (w * 2 + j) * 512);
        }
    };

    auto phase = [&](int d, int t3, int mp, auto stage, bool w8) {
        bf16x8 a[4][2], b2[2][2];
#pragma unroll
        for (int mf = 0; mf < 4; ++mf)
#pragma unroll
            for (int k2 = 0; k2 < 2; ++k2) {
                int r = mp * 128 + wmi * 64 + mf * 16 + lo;
                int u = quad + k2 * 4;
                a[mf][k2] = *(const bf16x8*)&lds[d * 16384 + r * 64 + ((u ^ (lo & 7)) << 3)];
            }
#pragma unroll
        for (int nf = 0; nf < 2; ++nf)
#pragma unroll
            for (int k2 = 0; k2 < 2; ++k2) {
                int r = wni * 32 + nf * 16 + lo;
                int u = quad + k2 * 4;
                b2[nf][k2] = *(const bf16x8*)&lds[32768 + t3 * 8192 + r * 64 + ((u ^ (lo & 7)) << 3)];
            }
        stage();
        __builtin_amdgcn_s_barrier();
        __builtin_amdgcn_sched_barrier(0);
        __builtin_amdgcn_s_setprio(1);
#pragma unroll
        for (int mf = 0; mf < 4; ++mf)
#pragma unroll
            for (int nf = 0; nf < 2; ++nf) {
                f32x4 z = acc[mp * 4 + mf][nf];
                z = MFMA16(a[mf][0], b2[nf][0], z);
                z = MFMA16(a[mf][1], b2[nf][1], z);
                acc[mp * 4 + mf][nf] = z;
            }
        __builtin_amdgcn_s_setprio(0);
        if (w8) asm volatile("s_waitcnt vmcnt(8)" ::: "memory");
        else    asm volatile("s_waitcnt vmcnt(6)" ::: "memory");
        __builtin_amdgcn_s_barrier();
        __builtin_amdgcn_sched_barrier(0);
    };

    stA(0, 0, 0); stA(0, 1, 0); stB(0);
    stA(1, 0, 1); stB(1);
    asm volatile("s_waitcnt vmcnt(4)" ::: "memory");
    __builtin_amdgcn_s_barrier();
    __builtin_amdgcn_sched_barrier(0);

    for (int i = 0; i < NIT; ++i) {
        int T0 = 2 * i, T1 = 2 * i + 1, T2 = 2 * i + 2, T3 = 2 * i + 3;
        int b0 = T0 % 3, b1 = T1 % 3;
        phase(0, b0, 0, [&] { stA(1, 1, T1); stB(T2); }, true);
        phase(0, b0, 1, [&] { stA(0, 0, T2); },          false);
        phase(1, b1, 0, [&] { stA(0, 1, T2); stB(T3); }, true);
        phase(1, b1, 1, [&] { stA(1, 0, T3); },          false);
    }

#pragma unroll
    for (int mi = 0; mi < 8; ++mi) {
        int mp = mi >> 2, mf = mi & 3;
        int row_base = m0 + mp * 128 + wmi * 64 + mf * 16 + quad * 4;
#pragma unroll
        for (int nf = 0; nf < 2; ++nf) {
            int col = n0 + wni * 32 + nf * 16 + lo;
#pragma unroll
            for (int r = 0; r < 4; ++r) {
                int row = row_base + r;
                if (Cf) Cf[(size_t)row * N + col] = acc[mi][nf][r];
                else    Cb[(size_t)row * N + col] = f2bf(acc[mi][nf][r]);
            }
        }
    }
}

// ---------------- RMSNorm + RoPE (+ scatter to outputs) ----------------
// qkv: (B*S, 3072) bf16 rows = [q 2048 | k 512 | v 512]
__global__ __launch_bounds__(256) void rmsrope_kernel(
    const unsigned short* __restrict__ qkv,
    const float* __restrict__ cosb, const float* __restrict__ sinb,
    const float* __restrict__ q_scale, const float* __restrict__ k_scale,
    unsigned short* __restrict__ q_attn, unsigned short* __restrict__ k_attn,
    float* __restrict__ k_out, float* __restrict__ v_out)
{
    int wid = blockIdx.x * 4 + (threadIdx.x >> 6);   // one wave per 64-elem row
    int lane = threadIdx.x & 63;
    int t = wid % 48;          // 0..31 q-head, 32..39 k-group, 40..47 v-group
    int bs = wid / 48;         // 0..4095
    int b = bs >> 11, s = bs & 2047;

    if (t >= 40) {             // v: straight copy to output (b,g,s,d) fp32
        int g = t - 40;
        float val = bf2f(qkv[(size_t)bs * 3072 + 2560 + g * 64 + lane]);
        v_out[(size_t)((b * 8 + g) * 2048 + s) * 64 + lane] = val;
        return;
    }
    bool is_q = (t < 32);
    int col = is_q ? (t * 64) : (2048 + (t - 32) * 64);
    float val = bf2f(qkv[(size_t)bs * 3072 + col + lane]);
    float ss = val * val;
#pragma unroll
    for (int m = 1; m < 64; m <<= 1) ss += __shfl_xor(ss, m);
    float rs = rsqrtf(ss * (1.0f / 64.0f) + 1e-6f);
    float scl = is_q ? q_scale[lane] : k_scale[lane];
    float xn = val * rs * scl;
    float other = __shfl_xor(xn, 32);
    float rot = (lane < 32) ? -other : other;     // [-x2, x1]
    float o = xn * cosb[s * 64 + lane] + rot * sinb[s * 64 + lane];
    if (is_q) {
        // fold 1/sqrt(D)=0.125 and log2(e) into q (attention works in exp2 domain)
        q_attn[(size_t)((b * 32 + t) * 2048 + s) * 64 + lane] = to_bf(o * (0.125f * 1.44269504f));
    } else {
        int g = t - 32;
        size_t idx = (size_t)((b * 8 + g) * 2048 + s) * 64 + lane;
        k_attn[idx] = to_bf(o);
        k_out[idx] = o;
    }
}

// ---------------- V transpose: qkv v-cols -> vt (b,g,d,s) bf16 ----------------
__global__ __launch_bounds__(256) void vtrans_kernel(
    const unsigned short* __restrict__ qkv, unsigned short* __restrict__ vt)
{
    __shared__ __align__(16) unsigned short sT[64 * 68];
    int idx = blockIdx.x;            // B*G*32 = 512
    int st = idx & 31, g = (idx >> 5) & 7, b = idx >> 8;
    int tid = threadIdx.x;
#pragma unroll
    for (int c = tid; c < 512; c += 256) {
        int r = c >> 3, cb = c & 7;
        *(uint4*)&sT[r * 68 + cb * 8] =
            *(const uint4*)&qkv[(size_t)(b * 2048 + st * 64 + r) * 3072 + 2560 + g * 64 + cb * 8];
    }
    __syncthreads();
#pragma unroll
    for (int c = tid; c < 512; c += 256) {
        int d = c >> 3, cb = c & 7;
        union { unsigned short e[8]; uint4 v; } u;
#pragma unroll
        for (int j = 0; j < 8; ++j) u.e[j] = sT[(cb * 8 + j) * 68 + d];
        *(uint4*)&vt[((size_t)(b * 8 + g) * 64 + d) * 2048 + st * 64 + cb * 8] = u.v;
    }
}

// ---------------- flash attention, causal, GQA ----------------
// R9 post-mortem: 64-row tiles regressed (2-blocks/CU grid + pairing imbalance
// -> makespan tail; occupancy 12.8%). REVERTED to the verified R8 structure
// (1024 blocks, 32 rows/wave, 90us) with ONE delta: sP padding (stride 68)
// replaced by a 16B-granule XOR swizzle (granule = (col>>3) ^ (row&7)), same
// involution on write and read. This cuts LDS 41472 -> 40960 = exactly
// 160KB/4, unlocking the 4th resident block per CU (grid offers 4; was
// LDS-capped at 3). Conflict cost: reads/writes go 0 -> <=2-way (rows 8 apart
// now alias banks); 2-way is free (m136).
__global__ __launch_bounds__(256, 2) void attn_kernel(
    const unsigned short* __restrict__ q_attn,   // (b,h,s,d) bf16, pre-scaled (log2 domain)
    const unsigned short* __restrict__ k_attn,   // (b,g,s,d) bf16 post-rope
    const unsigned short* __restrict__ vt,       // (b,g,d,s) bf16
    unsigned short* __restrict__ ctx)            // (b,s,h*d) bf16
{
    __shared__ __align__(16) unsigned short sK[2][4096];   // 16 KB (2 x 64x64 bf16)
    __shared__ __align__(16) unsigned short sV[2][4096];   // 16 KB
    __shared__ __align__(16) unsigned short sP[4][1024];   // 8 KB (wave-private, XOR-swizzled)

    int w = threadIdx.x >> 6;        // wave in block = head-in-group, 0..3
    int lane = threadIdx.x & 63;

    int g = blockIdx.x & 7;          // XCD swizzle: (b,g) working set pinned per XCD
    int ord = blockIdx.x >> 3;       // 0..127
    int b = ord & 1;
    int qt = 63 - (ord >> 1);        // 63..0: longest tasks dispatched first
    int h = g * 4 + w;

    int lo = lane & 15, quad = lane >> 4;
    int lo7 = lo & 7, lohi = lo >> 3;
    unsigned short* sPw = sP[w];

    const unsigned short* Qb = q_attn + (size_t)(b * 32 + h) * 2048 * 64;
    const unsigned short* Kb = k_attn + (size_t)(b * 8 + g) * 2048 * 64;
    const unsigned short* Vb = vt + (size_t)(b * 8 + g) * 64 * 2048;

    int nt = (qt >> 1) + 1;          // kv tiles 0..nt-1 (tile = 64 kv)

    int rsub = lane >> 3;                  // 0..7 (== row & 7 within chunk)
    int csw  = ((lane & 7) ^ rsub) << 3;   // ushort units

    auto STAGE = [&](int buf, int kt) {
#pragma unroll
        for (int i = 0; i < 2; ++i) {
            int c = w + i * 4;             // this wave's chunks: w, w+4
            gll16(Kb + (size_t)(kt * 64 + c * 8 + rsub) * 64 + csw, &sK[buf][c * 512]);
            gll16(Vb + (size_t)(c * 8 + rsub) * 2048 + kt * 64 + csw, &sV[buf][c * 512]);
        }
    };

    const bf16_t one = (bf16_t)1.0f;
    const bf16x8 vone = {one, one, one, one, one, one, one, one};

    bf16x8 qf[2][2];
#pragma unroll
    for (int mt = 0; mt < 2; ++mt)
#pragma unroll
        for (int h2 = 0; h2 < 2; ++h2)
            qf[mt][h2] = *(const bf16x8*)&Qb[(size_t)(qt * 32 + mt * 16 + lo) * 64 + h2 * 32 + quad * 8];

    f32x4 o_acc[2][4];
    f32x4 l_acc[2];
#pragma unroll
    for (int mt = 0; mt < 2; ++mt) {
        l_acc[mt] = (f32x4){0.f, 0.f, 0.f, 0.f};
#pragma unroll
        for (int j = 0; j < 4; ++j) o_acc[mt][j] = (f32x4){0.f, 0.f, 0.f, 0.f};
    }

    STAGE(0, 0);
    __syncthreads();                 // drains vmcnt(0): buffer 0 complete

    int cur = 0;
    for (int kt = 0; kt < nt; ++kt) {
        if (kt + 1 < nt) STAGE(cur ^ 1, kt + 1);   // issue-early, in flight during compute

        const char* sKc = (const char*)sK[cur];
        const char* sVc = (const char*)sV[cur];
        bool domask = (kt == nt - 1);

#pragma unroll
        for (int mt = 0; mt < 2; ++mt) {
            f32x4 sc[4];
            __builtin_amdgcn_s_setprio(1);
#pragma unroll
            for (int ct = 0; ct < 4; ++ct) {
                int krow = ct * 16 + lo;
                int rsw = (krow & 7) << 4;
                bf16x8 kf0 = *(const bf16x8*)(sKc + (krow << 7) + (((quad << 4)) ^ rsw));
                bf16x8 kf1 = *(const bf16x8*)(sKc + (krow << 7) + (((1 << 6) | (quad << 4)) ^ rsw));
                f32x4 z = (f32x4){0.f, 0.f, 0.f, 0.f};
                z = MFMA16(qf[mt][0], kf0, z);
                z = MFMA16(qf[mt][1], kf1, z);
                sc[ct] = z;
            }
            __builtin_amdgcn_s_setprio(0);
            if (domask) {
                int qrow0 = qt * 32 + mt * 16 + quad * 4;
#pragma unroll
                for (int ct = 0; ct < 4; ++ct)
#pragma unroll
                    for (int r = 0; r < 4; ++r)
                        if (kt * 64 + ct * 16 + lo > qrow0 + r) sc[ct][r] = -INFINITY;
            }
#pragma unroll
            for (int ct = 0; ct < 4; ++ct)
#pragma unroll
                for (int r = 0; r < 4; ++r)
                    sc[ct][r] = __builtin_amdgcn_exp2f(sc[ct][r]);

            // P -> LDS, stride 64 with 16B-granule XOR swizzle:
            //   u16 addr = row*64 + (((col>>3) ^ (row&7))<<3) + (col&7)
            // row = quad*4+r, col = ct*16+lo
#pragma unroll
            for (int ct = 0; ct < 4; ++ct)
#pragma unroll
                for (int r = 0; r < 4; ++r) {
                    int row = quad * 4 + r;
                    int gran = (2 * ct + lohi) ^ (row & 7);
                    sPw[(row << 6) + (gran << 3) + lo7] = to_bf(sc[ct][r]);
                }

            // reads: row = lo, cols [quad*8, quad*8+8) and [32+quad*8, ...)
            bf16x8 pf0 = *(const bf16x8*)&sPw[(lo << 6) + ((quad ^ lo7) << 3)];
            bf16x8 pf1 = *(const bf16x8*)&sPw[(lo << 6) + (((quad + 4) ^ lo7) << 3)];

            __builtin_amdgcn_s_setprio(1);
            l_acc[mt] = MFMA16(pf0, vone, l_acc[mt]);
            l_acc[mt] = MFMA16(pf1, vone, l_acc[mt]);

#pragma unroll
            for (int nt2 = 0; nt2 < 4; ++nt2) {
                int vrow = nt2 * 16 + lo;
                int rsw = (vrow & 7) << 4;
                bf16x8 vf0 = *(const bf16x8*)(sVc + (vrow << 7) + (((quad << 4)) ^ rsw));
                bf16x8 vf1 = *(const bf16x8*)(sVc + (vrow << 7) + (((1 << 6) | (quad << 4)) ^ rsw));
                f32x4 oo = o_acc[mt][nt2];
                oo = MFMA16(pf0, vf0, oo);
                oo = MFMA16(pf1, vf1, oo);
                o_acc[mt][nt2] = oo;
            }
            __builtin_amdgcn_s_setprio(0);
        }

        __syncthreads();
        cur ^= 1;
    }

#pragma unroll
    for (int mt = 0; mt < 2; ++mt)
#pragma unroll
        for (int r = 0; r < 4; ++r) {
            float inv = 1.0f / l_acc[mt][r];
            int row = qt * 32 + mt * 16 + quad * 4 + r;
#pragma unroll
            for (int nt2 = 0; nt2 < 4; ++nt2) {
                size_t oi = ((size_t)(b * 2048 + row)) * 2048 + h * 64 + nt2 * 16 + lo;
                ctx[oi] = to_bf(o_acc[mt][nt2][r] * inv);
            }
        }
}

// ---------------- launch ----------------
extern "C" void kernel_launch(void* const* d_in, const int* in_sizes, int n_in,
                              void* d_out, int out_size, void* d_ws, size_t ws_size,
                              hipStream_t stream)
{
    (void)in_sizes; (void)n_in; (void)out_size; (void)ws_size;
    const float* x       = (const float*)d_in[0];
    // d_in[1] = mask: ignored (causal mask recomputed analytically)
    const float* cosb    = (const float*)d_in[2];
    const float* sinb    = (const float*)d_in[3];
    const float* Wq      = (const float*)d_in[4];
    const float* Wk      = (const float*)d_in[5];
    const float* Wv      = (const float*)d_in[6];
    const float* Wo      = (const float*)d_in[7];
    const float* q_scale = (const float*)d_in[8];
    const float* k_scale = (const float*)d_in[9];

    float* out   = (float*)d_out;                 // (2,2048,2048)
    float* k_out = out + 8388608;                 // (2,8,2048,64)
    float* v_out = k_out + 2097152;               // (2,8,2048,64)

    // one-time: allow big dynamic LDS for the pipelined GEMMs
    static bool attr_done = false;
    if (!attr_done) {
        hipFuncSetAttribute((const void*)gemm256_bt,
                            hipFuncAttributeMaxDynamicSharedMemorySize, 131072);
        hipFuncSetAttribute((const void*)gemm256x128_bt,
                            hipFuncAttributeMaxDynamicSharedMemorySize, 114688);
        attr_done = true;
    }

    char* ws = (char*)d_ws;
    size_t off = 0;
    auto alloc = [&](size_t bytes) {
        char* p = ws + off; off += (bytes + 255) & ~(size_t)255; return p;
    };
    unsigned short* x_bf   = (unsigned short*)alloc(4096ull * 2048 * 2);   // 16 MB
    unsigned short* Wqkvt  = (unsigned short*)alloc(3072ull * 2048 * 2);   // 12 MB
    unsigned short* Wot    = (unsigned short*)alloc(2048ull * 2048 * 2);   //  8 MB
    unsigned short* qkv    = (unsigned short*)alloc(4096ull * 3072 * 2);   // 24 MB
    unsigned short* q_attn = (unsigned short*)alloc(4096ull * 2048 * 2);   // 16 MB
    unsigned short* k_attn = (unsigned short*)alloc(2048ull * 2048 * 2);   //  4 MB
    unsigned short* vt     = (unsigned short*)alloc(2097152ull * 2);       //  4 MB
    unsigned short* ctx    = (unsigned short*)alloc(4096ull * 2048 * 2);   // 16 MB

    cast_x_kernel<<<8192, 256, 0, stream>>>(x, x_bf, 8388608);
    castT_all_kernel<<<2560, 256, 0, stream>>>(Wq, Wk, Wv, Wo, Wqkvt, Wot);

    // qkv = x @ [Wq|Wk|Wv]  (bf16 out)
    gemm256_bt<<<dim3(12, 16), 512, 131072, stream>>>(x_bf, Wqkvt, nullptr, qkv, 4096, 3072, 2048);

    rmsrope_kernel<<<49152, 256, 0, stream>>>(qkv, cosb, sinb, q_scale, k_scale,
                                              q_attn, k_attn, k_out, v_out);
    vtrans_kernel<<<512, 256, 0, stream>>>(qkv, vt);

    attn_kernel<<<1024, 256, 0, stream>>>(q_attn, k_attn, vt, ctx);

    // out = ctx @ Wo  (fp32 out) — 256x128 tiles: 256 blocks, every CU busy
    gemm256x128_bt<<<dim3(16, 16), 512, 114688, stream>>>(ctx, Wot, out, nullptr, 4096, 2048, 2048);
}